// Round 1
// baseline (424.992 us; speedup 1.0000x reference)
//
#include <hip/hip_runtime.h>

// Problem constants (from reference): B=32, D=128, K=32, H=W=96 -> N=9216
#define B_ 32
#define D_ 128
#define K_ 32
#define N_ 9216
#define CHUNKS_ 72          // N / 128
#define AS_STRIDE 132       // A_s row stride (floats): b128-aligned, minimal bank passes
#define XS_STRIDE 132       // X_s row stride (floats)

__device__ __forceinline__ unsigned short f2bf(float f) {
    unsigned u = __float_as_uint(f);
    u += 0x7fffu + ((u >> 16) & 1u);   // round-to-nearest-even
    return (unsigned short)(u >> 16);
}
__device__ __forceinline__ float bf2f(unsigned short h) {
    return __uint_as_float(((unsigned)h) << 16);
}

// ---------------------------------------------------------------------------
// K1: per-position scaled-L2 softmax.  One thread per n.
// A out layout: [b][chunk=n>>7][k][n&127]  (bf16)  -> contiguous 32x128 tiles
// ---------------------------------------------------------------------------
__global__ __launch_bounds__(256) void k_softmax(
        const float* __restrict__ X, const float* __restrict__ cw,
        const float* __restrict__ scale, unsigned short* __restrict__ A) {
    __shared__ float s2_s[32];
    __shared__ float c2_s[32];
    const int t = threadIdx.x;
    const int blk = blockIdx.x;
    const int b = blk / 36;               // 36 blocks of 256 n per batch
    const int n = (blk % 36) * 256 + t;

    if (t < 32) {
        float sc = scale[t];
        s2_s[t] = sc * sc;
        const float4* c4p = (const float4*)(cw + t * 128);
        float s = 0.f;
        #pragma unroll 8
        for (int i = 0; i < 32; ++i) {
            float4 c = c4p[i];
            s += c.x * c.x + c.y * c.y + c.z * c.z + c.w * c.w;
        }
        c2_s[t] = s;
    }
    __syncthreads();

    const float* Xb = X + (size_t)b * (D_ * (size_t)N_) + n;
    float xc[32];
    #pragma unroll
    for (int k = 0; k < 32; ++k) xc[k] = 0.f;
    float x2 = 0.f;

    const float4* cw4 = (const float4*)cw;   // [k][d/4]
    #pragma unroll 4
    for (int d4 = 0; d4 < 32; ++d4) {
        // lane-coalesced reads (consecutive n across lanes)
        float xa0 = Xb[(size_t)(4 * d4 + 0) * N_];
        float xa1 = Xb[(size_t)(4 * d4 + 1) * N_];
        float xa2 = Xb[(size_t)(4 * d4 + 2) * N_];
        float xa3 = Xb[(size_t)(4 * d4 + 3) * N_];
        x2 += xa0 * xa0 + xa1 * xa1 + xa2 * xa2 + xa3 * xa3;
        #pragma unroll
        for (int k = 0; k < 32; ++k) {
            float4 c = cw4[k * 32 + d4];   // wave-uniform -> s_load
            xc[k] += xa0 * c.x + xa1 * c.y + xa2 * c.z + xa3 * c.w;
        }
    }

    // softmax over k of sl_k = scale_k^2 * (x2 - 2*xc_k + c2_k)
    float m = -3.0e38f;
    #pragma unroll
    for (int k = 0; k < 32; ++k) {
        float sl = s2_s[k] * (x2 - 2.f * xc[k] + c2_s[k]);
        xc[k] = sl;
        m = fmaxf(m, sl);
    }
    float ssum = 0.f;
    #pragma unroll
    for (int k = 0; k < 32; ++k) {
        float p = __expf(xc[k] - m);
        xc[k] = p;
        ssum += p;
    }
    const float inv = 1.f / ssum;

    const size_t abase =
        (((size_t)b * CHUNKS_ + (n >> 7)) * 32) * 128 + (n & 127);
    #pragma unroll
    for (int k = 0; k < 32; ++k) {
        A[abase + (size_t)k * 128] = f2bf(xc[k] * inv);   // lane-coalesced per k
    }
}

// ---------------------------------------------------------------------------
// K2: E[b,k,d] = sum_n A[n,k]*X[d,n] - (sum_n A[n,k])*c[k,d]
// grid = B * 24 blocks; each block handles 3 chunks of 128 n, accumulates in
// registers, one atomicAdd per owned output element at the end.
// Thread owns k in {kp, kp+16} (kp = t&15) and d = h*64 + 16*i + dg (dg = t>>4).
// ---------------------------------------------------------------------------
__global__ __launch_bounds__(256) void k_aggregate(
        const float* __restrict__ X, const unsigned short* __restrict__ A,
        const float* __restrict__ cw, float* __restrict__ out) {
    __shared__ float A_s[32 * AS_STRIDE];   // 16896 B
    __shared__ float X_s[64 * XS_STRIDE];   // 33792 B  (one 64-row half of d)
    const int t = threadIdx.x;
    const int blk = blockIdx.x;
    const int b = blk / 24;
    const int cg = blk % 24;
    const int kp = t & 15;
    const int dg = t >> 4;                  // 0..15

    float acc[2][2][4];                     // [kk][h][i]
    #pragma unroll
    for (int a = 0; a < 2; ++a)
        #pragma unroll
        for (int h = 0; h < 2; ++h)
            #pragma unroll
            for (int i = 0; i < 4; ++i) acc[a][h][i] = 0.f;
    float accS0 = 0.f, accS1 = 0.f;

    for (int cc = 0; cc < 3; ++cc) {
        const int ch = cg * 3 + cc;
        __syncthreads();                    // previous compute done before restage
        // ---- stage A chunk [32 k][128 j] bf16 -> fp32 LDS ----
        const unsigned short* Ab = A + (((size_t)b * CHUNKS_ + ch) * 32) * 128;
        #pragma unroll
        for (int i = 0; i < 4; ++i) {
            int f = t + 256 * i;            // ushort4 index (1024 total)
            ushort4 u = ((const ushort4*)Ab)[f];
            int k = f >> 5;
            int j = (f & 31) * 4;
            float4 v = make_float4(bf2f(u.x), bf2f(u.y), bf2f(u.z), bf2f(u.w));
            *(float4*)&A_s[k * AS_STRIDE + j] = v;
        }
        #pragma unroll
        for (int h = 0; h < 2; ++h) {
            __syncthreads();                // A_s ready / previous X_s consumed
            // ---- stage X half: rows r=0..63 -> d = h*64+r, cols = ch*128.. ----
            const float* Xb = X + ((size_t)b * D_ + h * 64) * (size_t)N_ + ch * 128;
            #pragma unroll
            for (int i = 0; i < 8; ++i) {
                int f = t + 256 * i;        // float4 index (2048 total)
                int r = f >> 5;
                int c4 = (f & 31) * 4;
                float4 v = *(const float4*)(Xb + (size_t)r * N_ + c4);
                *(float4*)&X_s[r * XS_STRIDE + c4] = v;
            }
            __syncthreads();
            // ---- compute ----
            for (int j4 = 0; j4 < 32; ++j4) {
                const int j = j4 * 4;
                float4 a0 = *(const float4*)&A_s[kp * AS_STRIDE + j];
                float4 a1 = *(const float4*)&A_s[(kp + 16) * AS_STRIDE + j];
                if (h == 0) {               // sumA once per chunk
                    accS0 += a0.x + a0.y + a0.z + a0.w;
                    accS1 += a1.x + a1.y + a1.z + a1.w;
                }
                #pragma unroll
                for (int i = 0; i < 4; ++i) {
                    float4 x = *(const float4*)&X_s[(dg + 16 * i) * XS_STRIDE + j];
                    acc[0][h][i] += a0.x * x.x + a0.y * x.y + a0.z * x.z + a0.w * x.w;
                    acc[1][h][i] += a1.x * x.x + a1.y * x.y + a1.z * x.z + a1.w * x.w;
                }
            }
        }
    }
    // ---- finalize: subtract block-partial sumA * c[k,d], atomic into E ----
    #pragma unroll
    for (int kk = 0; kk < 2; ++kk) {
        const int k = kp + kk * 16;
        const float as = kk ? accS1 : accS0;
        #pragma unroll
        for (int h = 0; h < 2; ++h) {
            #pragma unroll
            for (int i = 0; i < 4; ++i) {
                const int d = h * 64 + 16 * i + dg;
                float val = acc[kk][h][i] - as * cw[k * 128 + d];
                atomicAdd(out + ((size_t)b * 32 + k) * 128 + d, val);
            }
        }
    }
}

extern "C" void kernel_launch(void* const* d_in, const int* in_sizes, int n_in,
                              void* d_out, int out_size, void* d_ws, size_t ws_size,
                              hipStream_t stream) {
    const float* X     = (const float*)d_in[0];
    const float* cw    = (const float*)d_in[1];
    const float* scale = (const float*)d_in[2];
    float* out = (float*)d_out;
    unsigned short* A = (unsigned short*)d_ws;   // bf16 A: 32*9216*32*2 = 18.9 MB

    hipMemsetAsync(d_out, 0, (size_t)out_size * sizeof(float), stream);
    k_softmax  <<<dim3(B_ * 36), dim3(256), 0, stream>>>(X, cw, scale, A);
    k_aggregate<<<dim3(B_ * 24), dim3(256), 0, stream>>>(X, A, cw, out);
}

// Round 3
// 227.880 us; speedup vs baseline: 1.8650x; 1.8650x over previous
//
#include <hip/hip_runtime.h>

// B=32, D=128, K=32, N=9216. Fused softmax(scaled-L2)+aggregation, bf16 MFMA.
// Deterministic: per-block partials in d_ws + reduction kernel (no atomics).
#define B_ 32
#define D_ 128
#define K_ 32
#define N_ 9216
#define NT 256      // n per block
#define NS 64       // n per sub-chunk
#define XDN_S 72    // X_dn row stride (bf16 shorts)
#define AKN_S 72    // A_kn row stride
#define X2S_S 68    // x2 partial stride (floats)
// X_nd / CWb: stride 128 shorts, 16B-granule XOR swizzle: phys_g = g ^ (row&15)

typedef __bf16 bf16x8_t __attribute__((ext_vector_type(8)));
typedef float f32x4_t __attribute__((ext_vector_type(4)));

__device__ __forceinline__ unsigned short f2bf(float f) {
    unsigned u = __float_as_uint(f);
    u = (u + 0x7fffu + ((u >> 16) & 1u)) >> 16;
    return (unsigned short)u;
}
__device__ __forceinline__ unsigned f2bf_pk(float lo, float hi) {
    unsigned a = __float_as_uint(lo);
    a = (a + 0x7fffu + ((a >> 16) & 1u)) >> 16;
    unsigned b = __float_as_uint(hi);
    b = (b + 0x7fffu + ((b >> 16) & 1u)) & 0xffff0000u;
    return a | b;
}

__global__ __launch_bounds__(256, 3) void k_fused(
        const float* __restrict__ X, const float* __restrict__ cw,
        const float* __restrict__ scale, float* __restrict__ ws) {
    __shared__ __align__(16) unsigned short X_nd[NS * 128];     // 16384 B (swizzled)
    __shared__ __align__(16) unsigned short X_dn[D_ * XDN_S];   // 18432 B
    __shared__ __align__(16) unsigned short CWb[K_ * 128];      //  8192 B (swizzled)
    __shared__ __align__(16) unsigned short Akn[K_ * AKN_S];    //  4608 B
    __shared__ float x2s[16 * X2S_S];                           //  4352 B
    __shared__ float x2f[NS];
    __shared__ float u_s[K_], w_s[K_];
    __shared__ float sAw[4 * 34];
    __shared__ float sA[K_];

    const int t = threadIdx.x;
    const int w = t >> 6;          // wave 0..3
    const int l = t & 63;          // lane
    const int lm = l & 15;
    const int lq = l >> 4;         // 0..3
    const int b = blockIdx.x / 36;
    const int n0 = (blockIdx.x % 36) * NT;

    // ---- stage codewords -> bf16 LDS (swizzled granules) ----
    #pragma unroll
    for (int i = 0; i < 4; ++i) {
        int idx = t + 256 * i;                 // float4 id, 1024 total
        int k = idx >> 5, d4 = idx & 31;
        float4 c = ((const float4*)cw)[idx];
        int phys = (d4 >> 1) ^ (k & 15);
        unsigned* p = (unsigned*)&CWb[k * 128 + phys * 8 + (d4 & 1) * 4];
        p[0] = f2bf_pk(c.x, c.y);
        p[1] = f2bf_pk(c.z, c.w);
    }
    if (t < 32) {
        float sc = scale[t];
        float s2 = sc * sc;
        const float4* cr = (const float4*)(cw + t * 128);
        float c2 = 0.f;
        #pragma unroll 8
        for (int i = 0; i < 32; ++i) {
            float4 v = cr[i];
            c2 += v.x * v.x + v.y * v.y + v.z * v.z + v.w * v.w;
        }
        u_s[t] = s2;
        w_s[t] = s2 * c2;
    }
    __syncthreads();
    const float u0 = u_s[lm], u1 = u_s[16 + lm];
    const float w0 = w_s[lm], w1 = w_s[16 + lm];

    f32x4_t acc2[2][2];
    #pragma unroll
    for (int a = 0; a < 2; ++a)
        #pragma unroll
        for (int c = 0; c < 2; ++c)
            acc2[a][c] = (f32x4_t){0.f, 0.f, 0.f, 0.f};
    float ps0 = 0.f, ps1 = 0.f;

    const int n4 = t & 15;    // n-quad owned for staging
    const int d8 = t >> 4;    // d-octet owned for staging (0..15)

    for (int s = 0; s < 4; ++s) {
        __syncthreads();   // prior GEMM2 reads done before restage
        // ---- stage X[b, d8*8..+7, n0+s*64+n4*4..+3] ----
        const float* Xg = X + ((size_t)b * D_ + d8 * 8) * N_ + n0 + s * NS + n4 * 4;
        float4 v[8];
        #pragma unroll
        for (int j = 0; j < 8; ++j) v[j] = *(const float4*)(Xg + (size_t)j * N_);
        // x2 partials (fp32)
        #pragma unroll
        for (int jn = 0; jn < 4; ++jn) {
            float a = 0.f;
            #pragma unroll
            for (int j = 0; j < 8; ++j) {
                float xv = (&v[j].x)[jn];
                a += xv * xv;
            }
            x2s[d8 * X2S_S + n4 * 4 + jn] = a;
        }
        // X_dn [d][n]
        #pragma unroll
        for (int j = 0; j < 8; ++j) {
            unsigned* p = (unsigned*)&X_dn[(d8 * 8 + j) * XDN_S + n4 * 4];
            p[0] = f2bf_pk(v[j].x, v[j].y);
            p[1] = f2bf_pk(v[j].z, v[j].w);
        }
        // X_nd [n][d], XOR-swizzled granules (conflict-free writes & reads)
        #pragma unroll
        for (int jn = 0; jn < 4; ++jn) {
            unsigned q[4];
            #pragma unroll
            for (int j2 = 0; j2 < 4; ++j2)
                q[j2] = f2bf_pk((&v[2 * j2].x)[jn], (&v[2 * j2 + 1].x)[jn]);
            int row = n4 * 4 + jn;
            *(uint4*)&X_nd[row * 128 + (d8 ^ (row & 15)) * 8] = *(const uint4*)q;
        }
        __syncthreads();
        if (t < NS) {
            float a = 0.f;
            #pragma unroll
            for (int g = 0; g < 16; ++g) a += x2s[g * X2S_S + t];
            x2f[t] = a;
        }
        // ---- GEMM1: xc[n][k], wave w owns n-rows w*16..+15 ----
        f32x4_t acc1[2];
        acc1[0] = (f32x4_t){0.f, 0.f, 0.f, 0.f};
        acc1[1] = (f32x4_t){0.f, 0.f, 0.f, 0.f};
        #pragma unroll
        for (int ks = 0; ks < 4; ++ks) {
            int g = (ks * 4 + lq) ^ lm;    // swizzled granule
            bf16x8_t a  = *(const bf16x8_t*)&X_nd[(w * 16 + lm) * 128 + g * 8];
            bf16x8_t b0 = *(const bf16x8_t*)&CWb[lm * 128 + g * 8];
            bf16x8_t b1 = *(const bf16x8_t*)&CWb[(16 + lm) * 128 + g * 8];
            acc1[0] = __builtin_amdgcn_mfma_f32_16x16x32_bf16(a, b0, acc1[0], 0, 0, 0);
            acc1[1] = __builtin_amdgcn_mfma_f32_16x16x32_bf16(a, b1, acc1[1], 0, 0, 0);
        }
        __syncthreads();   // x2f visible; Akn free to overwrite
        // ---- softmax over k; C-layout: col(k)=lm, row(n)=lq*4+r ----
        #pragma unroll
        for (int r = 0; r < 4; ++r) {
            int nl = w * 16 + lq * 4 + r;
            float x2v = x2f[nl];
            float sl0 = u0 * x2v + w0 - 2.f * u0 * acc1[0][r];
            float sl1 = u1 * x2v + w1 - 2.f * u1 * acc1[1][r];
            float m = fmaxf(sl0, sl1);
            m = fmaxf(m, __shfl_xor(m, 1));
            m = fmaxf(m, __shfl_xor(m, 2));
            m = fmaxf(m, __shfl_xor(m, 4));
            m = fmaxf(m, __shfl_xor(m, 8));
            float p0 = __expf(sl0 - m);
            float p1 = __expf(sl1 - m);
            float sum = p0 + p1;
            sum += __shfl_xor(sum, 1);
            sum += __shfl_xor(sum, 2);
            sum += __shfl_xor(sum, 4);
            sum += __shfl_xor(sum, 8);
            float inv = 1.f / sum;
            p0 *= inv; p1 *= inv;
            ps0 += p0; ps1 += p1;
            Akn[lm * AKN_S + nl] = f2bf(p0);
            Akn[(16 + lm) * AKN_S + nl] = f2bf(p1);
        }
        __syncthreads();   // Akn ready
        // ---- GEMM2: E[d][k] += sum_n X^T[d][n] * A[n][k]; wave w: d-tiles {w, w+4} ----
        #pragma unroll
        for (int ks = 0; ks < 2; ++ks) {
            bf16x8_t xa0 = *(const bf16x8_t*)&X_dn[(w * 16 + lm) * XDN_S + ks * 32 + lq * 8];
            bf16x8_t xa1 = *(const bf16x8_t*)&X_dn[((w + 4) * 16 + lm) * XDN_S + ks * 32 + lq * 8];
            bf16x8_t pb0 = *(const bf16x8_t*)&Akn[lm * AKN_S + ks * 32 + lq * 8];
            bf16x8_t pb1 = *(const bf16x8_t*)&Akn[(16 + lm) * AKN_S + ks * 32 + lq * 8];
            acc2[0][0] = __builtin_amdgcn_mfma_f32_16x16x32_bf16(xa0, pb0, acc2[0][0], 0, 0, 0);
            acc2[0][1] = __builtin_amdgcn_mfma_f32_16x16x32_bf16(xa0, pb1, acc2[0][1], 0, 0, 0);
            acc2[1][0] = __builtin_amdgcn_mfma_f32_16x16x32_bf16(xa1, pb0, acc2[1][0], 0, 0, 0);
            acc2[1][1] = __builtin_amdgcn_mfma_f32_16x16x32_bf16(xa1, pb1, acc2[1][1], 0, 0, 0);
        }
    }

    // ---- block-partial sumA[k] ----
    ps0 += __shfl_xor(ps0, 16); ps0 += __shfl_xor(ps0, 32);
    ps1 += __shfl_xor(ps1, 16); ps1 += __shfl_xor(ps1, 32);
    if (l < 16) {
        sAw[w * 34 + l] = ps0;
        sAw[w * 34 + 16 + l] = ps1;
    }
    __syncthreads();
    if (t < 32) sA[t] = sAw[t] + sAw[34 + t] + sAw[68 + t] + sAw[102 + t];
    __syncthreads();

    // ---- epilogue: per-block partial (E_partial - sumA_partial * c) -> ws ----
    float* pout = ws + (size_t)blockIdx.x * (K_ * D_);
    #pragma unroll
    for (int di = 0; di < 2; ++di) {
        #pragma unroll
        for (int kt = 0; kt < 2; ++kt) {
            #pragma unroll
            for (int r = 0; r < 4; ++r) {
                int d = (w + di * 4) * 16 + lq * 4 + r;   // C row = M = d
                int k = kt * 16 + lm;                     // C col = N = k
                pout[k * 128 + d] = acc2[di][kt][r] - sA[k] * cw[k * 128 + d];
            }
        }
    }
}

// out[b,k,d] = sum over the 36 block-partials of batch b (deterministic order)
__global__ __launch_bounds__(256) void k_reduce(
        const float* __restrict__ ws, float* __restrict__ out) {
    int i = blockIdx.x * 256 + threadIdx.x;   // float4 index, 0..32767
    int b = i >> 10;                          // 4096/4 = 1024 float4 per batch
    int j = i & 1023;
    const float4* p = (const float4*)ws + (size_t)b * 36 * 1024 + j;
    float4 s = make_float4(0.f, 0.f, 0.f, 0.f);
    #pragma unroll
    for (int c = 0; c < 36; ++c) {
        float4 v = p[(size_t)c * 1024];
        s.x += v.x; s.y += v.y; s.z += v.z; s.w += v.w;
    }
    ((float4*)out)[i] = s;
}

extern "C" void kernel_launch(void* const* d_in, const int* in_sizes, int n_in,
                              void* d_out, int out_size, void* d_ws, size_t ws_size,
                              hipStream_t stream) {
    const float* X     = (const float*)d_in[0];
    const float* cw    = (const float*)d_in[1];
    const float* scale = (const float*)d_in[2];
    float* out = (float*)d_out;
    float* ws  = (float*)d_ws;     // 1152 * 4096 floats = 18.9 MB partials

    k_fused <<<dim3(B_ * 36), dim3(256), 0, stream>>>(X, cw, scale, ws);
    k_reduce<<<dim3(128),     dim3(256), 0, stream>>>(ws, out);
}